// Round 16
// baseline (182.946 us; speedup 1.0000x reference)
//
#include <hip/hip_runtime.h>

// ---------------------------------------------------------------------------
// SparseGRUBrain: N=70000, H=8, E=1.12M, B=8.
// Pipeline (per call): memset(cnt,cursor) -> hist(+calT transpose, rank) ->
//   alloc (block scan + one global atomic per block) -> pack_store (lane-
//   cooperative full-line 64B records {Wz,Wr,Wh,cal}) -> gru_main.
// R16: gru_main handles TWO neurons per wave: lane = nn*32 + s*8 + b
//   (nn = neuron half, s = 4 edge-slots, b = batch). Each lane accumulates
//   h-elements s and s+4; reduce-scatter is 6 shuffles/gate over masks 8,16
//   (never crossing the nn boundary). Tail cost amortized over 2 neurons;
//   wave count halves to 35000. Sparse/dense math packed f32x2 (R14).
// Workspace (bytes):
//   [0,      280K)   cnt
//   [448K,   +4)     cursor
//   [512K,   +560K)  rowCnt (int2 per neuron: {begin, count})
//   [1280K,  +4.5M)  rank
//   [5888K,  +2.3M)  calT ((N+1) x 8 f32)
//   [8320K,  +72M)   recs (E x 64B records)
// ---------------------------------------------------------------------------

typedef float f2 __attribute__((ext_vector_type(2)));

__device__ __forceinline__ float fast_sigmoid(float x) {
    return 1.0f / (1.0f + __expf(-x));
}
__device__ __forceinline__ float fast_tanh(float x) {
    return 2.0f / (1.0f + __expf(-2.0f * x)) - 1.0f;
}

// fp32 -> bf16 bits, round-to-nearest-even
__device__ __forceinline__ unsigned bfr(float x) {
    unsigned u = __float_as_uint(x);
    return (u + 0x7fffu + ((u >> 16) & 1u)) >> 16;
}
__device__ __forceinline__ uint4 pack8(float4 a, float4 b) {
    uint4 r;
    r.x = bfr(a.x) | (bfr(a.y) << 16);
    r.y = bfr(a.z) | (bfr(a.w) << 16);
    r.z = bfr(b.x) | (bfr(b.y) << 16);
    r.w = bfr(b.z) | (bfr(b.w) << 16);
    return r;
}

// unpack 8 bf16 from uint4 into 4 float2 pairs, packed-fma with splatted c2
#define BFMA2(acc, p, c2)                                                      \
    {                                                                          \
        f2 w;                                                                  \
        w.x = __uint_as_float((p).x << 16);                                    \
        w.y = __uint_as_float((p).x & 0xffff0000u);                            \
        acc[0] = __builtin_elementwise_fma(w, c2, acc[0]);                     \
        w.x = __uint_as_float((p).y << 16);                                    \
        w.y = __uint_as_float((p).y & 0xffff0000u);                            \
        acc[1] = __builtin_elementwise_fma(w, c2, acc[1]);                     \
        w.x = __uint_as_float((p).z << 16);                                    \
        w.y = __uint_as_float((p).z & 0xffff0000u);                            \
        acc[2] = __builtin_elementwise_fma(w, c2, acc[2]);                     \
        w.x = __uint_as_float((p).w << 16);                                    \
        w.y = __uint_as_float((p).w & 0xffff0000u);                            \
        acc[3] = __builtin_elementwise_fma(w, c2, acc[3]);                     \
    }

// cnt[t]++ per edge (atomic return = rank within bucket); threads <= N also
// build calT (transpose of calcium, row N zeroed).
__global__ void hist_kernel(const int* __restrict__ tgt, int* __restrict__ cnt,
                            int* __restrict__ rank, const float* __restrict__ cal,
                            float* __restrict__ calT, int N, int E) {
    int i = blockIdx.x * blockDim.x + threadIdx.x;
    if (i <= N) {
        float4* o = (float4*)(calT + (size_t)i * 8);
        if (i == N) {
            o[0] = make_float4(0.f, 0.f, 0.f, 0.f);
            o[1] = make_float4(0.f, 0.f, 0.f, 0.f);
        } else {
            float v[8];
#pragma unroll
            for (int b = 0; b < 8; ++b) v[b] = cal[(size_t)b * N + i];
            o[0] = make_float4(v[0], v[1], v[2], v[3]);
            o[1] = make_float4(v[4], v[5], v[6], v[7]);
        }
    }
    int base = i * 4;
    if (base + 3 < E) {
        int4 t = *(const int4*)(tgt + base);
        int4 r;
        r.x = atomicAdd(&cnt[t.x], 1);
        r.y = atomicAdd(&cnt[t.y], 1);
        r.z = atomicAdd(&cnt[t.z], 1);
        r.w = atomicAdd(&cnt[t.w], 1);
        *(int4*)(rank + base) = r;
    } else {
        for (int k = base; k < E; ++k) rank[k] = atomicAdd(&cnt[tgt[k]], 1);
    }
}

// Row allocation without a global scan: block-local exclusive scan of cnt,
// one atomicAdd(cursor, blockTotal) per block. Writes rowCnt = {begin, count}.
__global__ __launch_bounds__(256) void alloc_kernel(const int* __restrict__ cnt,
                                                    int2* __restrict__ rowCnt,
                                                    int* __restrict__ cursor, int N) {
    __shared__ int waveSum[4];
    const int n = blockIdx.x * 256 + threadIdx.x;
    const int lane = threadIdx.x & 63;
    const int wid = threadIdx.x >> 6;
    int c = (n < N) ? cnt[n] : 0;
    int pre = c;
#pragma unroll
    for (int off = 1; off < 64; off <<= 1) {
        int v = __shfl_up(pre, off, 64);
        if (lane >= off) pre += v;
    }
    if (lane == 63) waveSum[wid] = pre;
    __syncthreads();
    if (threadIdx.x == 0) {
        int s0 = waveSum[0], s1 = waveSum[1], s2 = waveSum[2], s3 = waveSum[3];
        int base = atomicAdd(cursor, s0 + s1 + s2 + s3);
        waveSum[0] = base;
        waveSum[1] = base + s0;
        waveSum[2] = base + s0 + s1;
        waveSum[3] = base + s0 + s1 + s2;
    }
    __syncthreads();
    if (n < N) rowCnt[n] = make_int2(waveSum[wid] + (pre - c), c);
}

// LANE-COOPERATIVE packer: 4 consecutive lanes own one edge. Lane q packs
// quarter q of the 64B record (q=0..2: W rows; q=3: calT[src]) and stores one
// uint4 at recs[pos*4+q] -> each record is one fully-dirty 64B line.
__global__ __launch_bounds__(256) void pack_store(
    const int* __restrict__ src, const int* __restrict__ tgt,
    const int* __restrict__ rank, const int2* __restrict__ rowCnt,
    const float* __restrict__ Wz, const float* __restrict__ Wr,
    const float* __restrict__ Wh, const float* __restrict__ calT,
    uint4* __restrict__ recs, int E) {
    int gid = blockIdx.x * 256 + threadIdx.x;
    int e = gid >> 2;
    int q = gid & 3;
    if (e >= E) return;
    int t = tgt[e];                        // broadcast across the 4 lanes
    int pos = rowCnt[t].x + rank[e];
    const float* base;
    size_t off;
    if (q == 0)      { base = Wz;   off = (size_t)e * 8; }
    else if (q == 1) { base = Wr;   off = (size_t)e * 8; }
    else if (q == 2) { base = Wh;   off = (size_t)e * 8; }
    else             { base = calT; off = (size_t)src[e] * 8; }
    const float4* p = (const float4*)(base + off);
    float4 a = p[0], b = p[1];
    recs[(size_t)pos * 4 + q] = pack8(a, b);
}

// xor reduce-scatter over the 4 s-lanes (masks 8,16): input v[0..3] f2 pairs
// {a0,a1},{a2,a3},{a4,a5},{a6,a7}; output f2 {elem s, elem s+4} fully reduced.
__device__ __forceinline__ f2 rscatter2(const f2 v[4], bool s0, bool s1) {
    float w0, w1, w2, w3;
    { float k = s0 ? v[0].y : v[0].x, g = s0 ? v[0].x : v[0].y; w0 = k + __shfl_xor(g, 8, 64); }
    { float k = s0 ? v[1].y : v[1].x, g = s0 ? v[1].x : v[1].y; w1 = k + __shfl_xor(g, 8, 64); }
    { float k = s0 ? v[2].y : v[2].x, g = s0 ? v[2].x : v[2].y; w2 = k + __shfl_xor(g, 8, 64); }
    { float k = s0 ? v[3].y : v[3].x, g = s0 ? v[3].x : v[3].y; w3 = k + __shfl_xor(g, 8, 64); }
    f2 r;
    { float k = s1 ? w1 : w0, g = s1 ? w0 : w1; r.x = k + __shfl_xor(g, 16, 64); }
    { float k = s1 ? w3 : w2, g = s1 ? w2 : w3; r.y = k + __shfl_xor(g, 16, 64); }
    return r;
}

// Main: TWO neurons per wave, 256-thread blocks (8 neurons/block).
// lane = nn*32 + s*8 + b; lane accumulates h-elements s and s+4 of neuron nn.
__global__ __launch_bounds__(256) void gru_main(
    const float* __restrict__ hidden, const uint4* __restrict__ recs,
    const float* __restrict__ Uz, const float* __restrict__ Ur,
    const float* __restrict__ Uh, const float* __restrict__ bz,
    const float* __restrict__ br, const float* __restrict__ bh,
    const float* __restrict__ proj, const int2* __restrict__ rowCnt,
    float* __restrict__ outCal, float* __restrict__ outHid, int N) {
    const int lane = threadIdx.x & 63;
    const int wid = threadIdx.x >> 6;
    const int nn = lane >> 5;        // neuron half within the wave
    const int s = (lane >> 3) & 3;   // edge slot / low h index
    const int b = lane & 7;          // batch
    const int n = blockIdx.x * 8 + wid * 2 + nn;
    if (n >= N) return;              // whole 32-lane half returns together

    const bool s0 = (lane & 8) != 0;
    const bool s1 = (lane & 16) != 0;

    const int2 rc = rowCnt[n];
    const int start = rc.x;
    const int end = rc.x + rc.y;

    // ---- hoisted loads for the z/r path (hide under the sparse loop) ----
    const size_t hb = ((size_t)(b * N + n)) << 3;
    const float hv_lo = hidden[hb + s];
    const float hv_hi = hidden[hb + s + 4];
    const int ub_lo = (n << 6) + (s << 3);   // U row h=s
    const int ub_hi = ub_lo + 32;            // U row h=s+4
    f2 uzl[4], uzh[4], url[4], urh[4];
#pragma unroll
    for (int k = 0; k < 4; ++k) {
        uzl[k] = ((const f2*)(Uz + ub_lo))[k];
        uzh[k] = ((const f2*)(Uz + ub_hi))[k];
        url[k] = ((const f2*)(Ur + ub_lo))[k];
        urh[k] = ((const f2*)(Ur + ub_hi))[k];
    }
    const float bz_lo = bz[(n << 3) + s], bz_hi = bz[(n << 3) + s + 4];
    const float br_lo = br[(n << 3) + s], br_hi = br[(n << 3) + s + 4];

    f2 az2[4], ar2[4], ah2[4];
#pragma unroll
    for (int k = 0; k < 4; ++k) {
        az2[k] = (f2){0.0f, 0.0f};
        ar2[k] = (f2){0.0f, 0.0f};
        ah2[k] = (f2){0.0f, 0.0f};
    }

    // ---- sparse phase: slot s streams records j = start+s, +4, ... ----
    const unsigned short* recsH = (const unsigned short*)recs;
    for (int j = start + s; j < end; j += 4) {
        const uint4* rp = recs + (size_t)j * 4;
        uint4 pz = rp[0];
        uint4 pr = rp[1];
        uint4 ph = rp[2];
        unsigned cb = recsH[((size_t)j << 5) + 24 + b];
        float c = __uint_as_float(cb << 16);
        f2 c2 = {c, c};
        BFMA2(az2, pz, c2);
        BFMA2(ar2, pr, c2);
        BFMA2(ah2, ph, c2);
    }

    // ---- dense z/r partials for h = s and h = s+4 ----
    f2 hvl2 = {hv_lo, hv_lo};
    f2 hvh2 = {hv_hi, hv_hi};
#pragma unroll
    for (int k = 0; k < 4; ++k) {
        az2[k] = __builtin_elementwise_fma(uzl[k], hvl2, az2[k]);
        az2[k] = __builtin_elementwise_fma(uzh[k], hvh2, az2[k]);
        ar2[k] = __builtin_elementwise_fma(url[k], hvl2, ar2[k]);
        ar2[k] = __builtin_elementwise_fma(urh[k], hvh2, ar2[k]);
    }

    // ---- issue h-path loads now; latency hides under the shuffle chains ----
    f2 uhl[4], uhh[4];
#pragma unroll
    for (int k = 0; k < 4; ++k) {
        uhl[k] = ((const f2*)(Uh + ub_lo))[k];
        uhh[k] = ((const f2*)(Uh + ub_hi))[k];
    }
    const float bh_lo = bh[(n << 3) + s], bh_hi = bh[(n << 3) + s + 4];
    const float pj_lo = proj[s], pj_hi = proj[s + 4];

    // ---- reduce-scatter -> f2 {elem s, elem s+4} ----
    f2 AZ = rscatter2(az2, s0, s1);
    f2 AR = rscatter2(ar2, s0, s1);
    float z_lo = fast_sigmoid(AZ.x + bz_lo);
    float z_hi = fast_sigmoid(AZ.y + bz_hi);
    float r_lo = fast_sigmoid(AR.x + br_lo);
    float r_hi = fast_sigmoid(AR.y + br_hi);

    f2 rhl2 = {r_lo * hv_lo, r_lo * hv_lo};
    f2 rhh2 = {r_hi * hv_hi, r_hi * hv_hi};
#pragma unroll
    for (int k = 0; k < 4; ++k) {
        ah2[k] = __builtin_elementwise_fma(uhl[k], rhl2, ah2[k]);
        ah2[k] = __builtin_elementwise_fma(uhh[k], rhh2, ah2[k]);
    }
    f2 AH = rscatter2(ah2, s0, s1);
    float ht_lo = fast_tanh(AH.x + bh_lo);
    float ht_hi = fast_tanh(AH.y + bh_hi);
    float hn_lo = (1.0f - z_lo) * hv_lo + z_lo * ht_lo;
    float hn_hi = (1.0f - z_hi) * hv_hi + z_hi * ht_hi;

    // ---- projection: reduce over the 4 s-lanes (masks 8,16) ----
    float cv = hn_lo * pj_lo + hn_hi * pj_hi;
    cv += __shfl_xor(cv, 8, 64);
    cv += __shfl_xor(cv, 16, 64);

    outHid[hb + s] = hn_lo;
    outHid[hb + s + 4] = hn_hi;
    if ((lane & 24) == 0) outCal[b * N + n] = fmaxf(cv, 0.0f);
}

extern "C" void kernel_launch(void* const* d_in, const int* in_sizes, int n_in,
                              void* d_out, int out_size, void* d_ws, size_t ws_size,
                              hipStream_t stream) {
    const float* calcium = (const float*)d_in[0];
    const float* hidden  = (const float*)d_in[1];
    const int*   src     = (const int*)d_in[2];
    const int*   tgt     = (const int*)d_in[3];
    const float* Wz      = (const float*)d_in[4];
    const float* Wr      = (const float*)d_in[5];
    const float* Wh      = (const float*)d_in[6];
    const float* Uz      = (const float*)d_in[7];
    const float* Ur      = (const float*)d_in[8];
    const float* Uh      = (const float*)d_in[9];
    const float* bz      = (const float*)d_in[10];
    const float* br      = (const float*)d_in[11];
    const float* bh      = (const float*)d_in[12];
    const float* proj    = (const float*)d_in[13];

    const int E = in_sizes[2];
    const int H = in_sizes[13];           // 8
    const int N = in_sizes[10] / H;       // 70000
    (void)n_in; (void)out_size; (void)ws_size;

    float* out = (float*)d_out;
    float* outCal = out;
    float* outHid = out + (size_t)in_sizes[0];

    char* ws = (char*)d_ws;
    int*   cnt    = (int*)ws;
    int*   cursor = (int*)(ws + (448 << 10));
    int2*  rowCnt = (int2*)(ws + (512 << 10));
    int*   rank   = (int*)(ws + (1280 << 10));
    float* calT   = (float*)(ws + (5888 << 10));
    uint4* recs   = (uint4*)(ws + (8320 << 10));

    // zero cnt [0,280K) and cursor (at 448K) in one memset
    hipMemsetAsync(ws, 0, (448 << 10) + 4, stream);

    int histThreads = (E + 3) / 4;  // 280000 >= N+1, covers calT duty too
    hist_kernel<<<(histThreads + 255) / 256, 256, 0, stream>>>(
        tgt, cnt, rank, calcium, calT, N, E);
    alloc_kernel<<<(N + 255) / 256, 256, 0, stream>>>(cnt, rowCnt, cursor, N);
    {
        long long pthreads = (long long)E * 4;
        pack_store<<<(int)((pthreads + 255) / 256), 256, 0, stream>>>(
            src, tgt, rank, rowCnt, Wz, Wr, Wh, calT, recs, E);
    }
    gru_main<<<(N + 7) / 8, 256, 0, stream>>>(
        hidden, recs, Uz, Ur, Uh, bz, br, bh, proj,
        rowCnt, outCal, outHid, N);
}